// Round 8
// baseline (331.793 us; speedup 1.0000x reference)
//
#include <hip/hip_runtime.h>
#include <hip/hip_cooperative_groups.h>
#include <math.h>

namespace cg = cooperative_groups;

// HW exp2 (v_exp_f32) when available.
#if defined(__has_builtin)
#  if __has_builtin(__builtin_amdgcn_exp2f)
#    define EXP2F(x) __builtin_amdgcn_exp2f(x)
#  endif
#endif
#ifndef EXP2F
#  define EXP2F(x) __expf(0.69314718055994530942f * (x))
#endif

// ---------------------------------------------------------------------------
// 4-layer OR-gate net.
//   aw = leaky_clamp(W,0,1,0.1); z = h*aw
//   out[b,o] = sum_i z*softmax_i(tau*z); h' = 1-out
// Folding: arg = c2*z (c2 = tau*log2 e); e = exp2(arg); out = t/(s*c2).
//
// Prepass computes cw[o,i] = c2*leaky_clamp(W[o,i]) so the per-z inner loop
// is 3 full-rate + 1 trans op. Primary path: ONE cooperative launch with
// grid.sync() between layers (kills ~3 launch/drain gaps). Fallback if the
// cooperative launch is rejected (R6: failed silently -> all-zero output):
// prep kernel + 4 plain launches, the known-good R4 structure.
// ---------------------------------------------------------------------------

__device__ __forceinline__ float calc_c2(const float* tau_ptr, float tf) {
  const float ta  = tau_ptr[0];
  const float tau = tf + (ta >= 0.0f ? ta : 0.05f * ta);
  return tau * 1.44269504088896340736f;  // tau * log2(e)
}

// Elementwise: cw = c2 * leaky_clamp(W), float4-vectorized, grid-stride.
__device__ __forceinline__ void prep_cw(const float* __restrict__ W,
                                        float* __restrict__ cw,
                                        int n4, float c2, int gtid, int gsz) {
  const float4* __restrict__ Wv = (const float4*)W;
  float4* __restrict__ Cv = (float4*)cw;
  for (int k = gtid; k < n4; k += gsz) {
    float4 v = Wv[k];
    float w[4] = {v.x, v.y, v.z, v.w};
    float o[4];
#pragma unroll
    for (int j = 0; j < 4; ++j) {
      const float m  = fminf(fmaxf(w[j], 0.0f), 1.0f);
      const float aw = fmaf(0.1f, w[j] - m, m);
      o[j] = c2 * aw;
    }
    float4 r; r.x = o[0]; r.y = o[1]; r.z = o[2]; r.w = o[3];
    Cv[k] = r;
  }
}

// One layer. lane = il(16 over i) x og(4 o-groups), OBB=2 outputs per group
// -> 8 outputs/wave; 4 waves/block -> 32 outputs/block; BB batch rows.
// bid in [0, (OUT/32)*(128/BB)).
template <int IN, int OUT, int BB, bool FIRST>
__device__ __forceinline__ void layer_body(const float* __restrict__ hin,
                                           const float* __restrict__ cw,
                                           float* __restrict__ hout,
                                           float c2, int bid, int tid) {
  constexpr int OBB = 2;
  constexpr int NIT = IN / 64;           // 16 lanes x float4 per iter
  constexpr int nOT = OUT / 32;

  const int lane = tid & 63;
  const int wid  = tid >> 6;
  const int il   = lane & 15;
  const int og   = lane >> 4;

  const int ot = bid % nOT;
  const int bt = bid / nOT;
  const int b0 = bt * BB;
  const int o0 = ot * 32 + wid * 8 + og * OBB;

  const float4* __restrict__ Cv = (const float4*)cw;
  const float4* __restrict__ Hv = (const float4*)hin;

  float s[BB][OBB], t[BB][OBB];
#pragma unroll
  for (int r = 0; r < BB; ++r)
#pragma unroll
    for (int c = 0; c < OBB; ++c) { s[r][c] = 0.0f; t[r][c] = 0.0f; }

#pragma unroll 2
  for (int ic = 0; ic < NIT; ++ic) {
    const int i4 = ic * 16 + il;

    float hc[BB][4];
    if (FIRST) {
      // hin is x: (128, IN/2); h = concat(x, 1-x); 64-float chunks align with
      // the IN/2 boundary -> uniform branch.
      constexpr int HALF4 = IN / 8;
      if (i4 < HALF4) {
#pragma unroll
        for (int r = 0; r < BB; ++r) {
          float4 v = Hv[(b0 + r) * HALF4 + i4];
          hc[r][0] = v.x; hc[r][1] = v.y; hc[r][2] = v.z; hc[r][3] = v.w;
        }
      } else {
#pragma unroll
        for (int r = 0; r < BB; ++r) {
          float4 v = Hv[(b0 + r) * HALF4 + (i4 - HALF4)];
          hc[r][0] = 1.0f - v.x; hc[r][1] = 1.0f - v.y;
          hc[r][2] = 1.0f - v.z; hc[r][3] = 1.0f - v.w;
        }
      }
    } else {
#pragma unroll
      for (int r = 0; r < BB; ++r) {
        float4 v = Hv[(b0 + r) * (IN / 4) + i4];
        hc[r][0] = v.x; hc[r][1] = v.y; hc[r][2] = v.z; hc[r][3] = v.w;
      }
    }

    float a[OBB][4];
#pragma unroll
    for (int c = 0; c < OBB; ++c) {
      float4 v = Cv[(o0 + c) * (IN / 4) + i4];
      a[c][0] = v.x; a[c][1] = v.y; a[c][2] = v.z; a[c][3] = v.w;
    }

#pragma unroll
    for (int r = 0; r < BB; ++r)
#pragma unroll
      for (int c = 0; c < OBB; ++c)
#pragma unroll
        for (int j = 0; j < 4; ++j) {
          const float arg = a[c][j] * hc[r][j];
          const float e   = EXP2F(arg);
          s[r][c] += e;
          t[r][c]  = fmaf(arg, e, t[r][c]);
        }
  }

#pragma unroll
  for (int m = 1; m < 16; m <<= 1) {
#pragma unroll
    for (int r = 0; r < BB; ++r)
#pragma unroll
      for (int c = 0; c < OBB; ++c) {
        s[r][c] += __shfl_xor(s[r][c], m, 64);
        t[r][c] += __shfl_xor(t[r][c], m, 64);
      }
  }

  if (il == 0) {
    const float inv_c2 = 1.0f / c2;
#pragma unroll
    for (int r = 0; r < BB; ++r)
#pragma unroll
      for (int c = 0; c < OBB; ++c) {
        const float out = t[r][c] / s[r][c] * inv_c2;
        hout[(b0 + r) * OUT + (o0 + c)] = 1.0f - out;
      }
  }
}

// ---------------- fused cooperative kernel ----------------
__launch_bounds__(256, 2)   // cap VGPR <= 256 so 512 blocks = 2/CU co-reside
__global__ void or_fused(const float* __restrict__ x,
                         const float* __restrict__ W0, const float* __restrict__ W1,
                         const float* __restrict__ W2, const float* __restrict__ W3,
                         const float* __restrict__ tau0, const float* __restrict__ tau1,
                         const float* __restrict__ tau2, const float* __restrict__ tau3,
                         float* __restrict__ h1, float* __restrict__ h2,
                         float* __restrict__ h3, float* __restrict__ out,
                         float* __restrict__ cw0, float* __restrict__ cw1,
                         float* __restrict__ cw2, float* __restrict__ cw3,
                         float tf0, float tf1, float tf2, float tf3) {
  cg::grid_group grid = cg::this_grid();
  const int tid  = threadIdx.x;
  const int bid  = blockIdx.x;
  const int gtid = bid * 256 + tid;
  const int gsz  = gridDim.x * 256;

  const float c2_0 = calc_c2(tau0, tf0);
  const float c2_1 = calc_c2(tau1, tf1);
  const float c2_2 = calc_c2(tau2, tf2);
  const float c2_3 = calc_c2(tau3, tf3);

  prep_cw(W0, cw0, 1024 * 1024 / 4, c2_0, gtid, gsz);
  prep_cw(W1, cw1,  512 * 1024 / 4, c2_1, gtid, gsz);
  prep_cw(W2, cw2,  256 *  512 / 4, c2_2, gtid, gsz);
  prep_cw(W3, cw3,  128 *  256 / 4, c2_3, gtid, gsz);
  grid.sync();

  layer_body<1024, 1024, 8, true >(x, cw0, h1, c2_0, bid, tid);   // 512 blocks
  grid.sync();
  if (bid < 256) layer_body<1024, 512, 8, false>(h1, cw1, h2, c2_1, bid, tid);
  grid.sync();
  if (bid < 256) layer_body<512, 256, 4, false>(h2, cw2, h3, c2_2, bid, tid);
  grid.sync();
  if (bid < 256) layer_body<256, 128, 2, false>(h3, cw3, out, c2_3, bid, tid);
}

// ---------------- fallback: plain launches ----------------
__launch_bounds__(256)
__global__ void prep_all(const float* __restrict__ W0, const float* __restrict__ W1,
                         const float* __restrict__ W2, const float* __restrict__ W3,
                         const float* __restrict__ tau0, const float* __restrict__ tau1,
                         const float* __restrict__ tau2, const float* __restrict__ tau3,
                         float* __restrict__ cw0, float* __restrict__ cw1,
                         float* __restrict__ cw2, float* __restrict__ cw3,
                         float tf0, float tf1, float tf2, float tf3) {
  const int gtid = blockIdx.x * 256 + threadIdx.x;
  const int gsz  = gridDim.x * 256;
  prep_cw(W0, cw0, 1024 * 1024 / 4, calc_c2(tau0, tf0), gtid, gsz);
  prep_cw(W1, cw1,  512 * 1024 / 4, calc_c2(tau1, tf1), gtid, gsz);
  prep_cw(W2, cw2,  256 *  512 / 4, calc_c2(tau2, tf2), gtid, gsz);
  prep_cw(W3, cw3,  128 *  256 / 4, calc_c2(tau3, tf3), gtid, gsz);
}

template <int IN, int OUT, int BB, bool FIRST>
__launch_bounds__(256)
__global__ void or_layer_k(const float* __restrict__ hin,
                           const float* __restrict__ cw,
                           const float* __restrict__ tau_ptr,
                           float* __restrict__ hout, float tf) {
  layer_body<IN, OUT, BB, FIRST>(hin, cw, hout, calc_c2(tau_ptr, tf),
                                 blockIdx.x, threadIdx.x);
}

extern "C" void kernel_launch(void* const* d_in, const int* in_sizes, int n_in,
                              void* d_out, int out_size, void* d_ws, size_t ws_size,
                              hipStream_t stream) {
  // setup_inputs() dict order: x, W0, tau0, W1, tau1, W2, tau2, W3, tau3
  const float* x    = (const float*)d_in[0];
  const float* W0   = (const float*)d_in[1];
  const float* tau0 = (const float*)d_in[2];
  const float* W1   = (const float*)d_in[3];
  const float* tau1 = (const float*)d_in[4];
  const float* W2   = (const float*)d_in[5];
  const float* tau2 = (const float*)d_in[6];
  const float* W3   = (const float*)d_in[7];
  const float* tau3 = (const float*)d_in[8];

  float* h1  = (float*)d_ws;             // 128*1024
  float* h2  = h1 + 128 * 1024;          // 128*512
  float* h3  = h2 + 128 * 512;           // 128*256
  float* cw0 = h3 + 128 * 256;           // 1024*1024
  float* cw1 = cw0 + 1024 * 1024;        // 512*1024
  float* cw2 = cw1 + 512 * 1024;         // 256*512
  float* cw3 = cw2 + 256 * 512;          // 128*256
  float* out = (float*)d_out;            // 128*128

  const double LOGR = 2.9444389791664403;  // log(0.95) - log(0.05) = log(19)
  float tf0 = (float)(log(1023.0) + LOGR);
  float tf1 = (float)(log(1023.0) + LOGR);
  float tf2 = (float)(log(511.0)  + LOGR);
  float tf3 = (float)(log(255.0)  + LOGR);

  void* args[] = {
    (void*)&x,
    (void*)&W0, (void*)&W1, (void*)&W2, (void*)&W3,
    (void*)&tau0, (void*)&tau1, (void*)&tau2, (void*)&tau3,
    (void*)&h1, (void*)&h2, (void*)&h3, (void*)&out,
    (void*)&cw0, (void*)&cw1, (void*)&cw2, (void*)&cw3,
    (void*)&tf0, (void*)&tf1, (void*)&tf2, (void*)&tf3,
  };
  hipError_t err = hipLaunchCooperativeKernel((void*)or_fused, dim3(512),
                                              dim3(256), args, 0, stream);
  if (err != hipSuccess) {
    // Fallback: prep + 4 plain launches (R4 structure, known-good).
    prep_all<<<256, 256, 0, stream>>>(W0, W1, W2, W3, tau0, tau1, tau2, tau3,
                                      cw0, cw1, cw2, cw3, tf0, tf1, tf2, tf3);
    or_layer_k<1024, 1024, 8, true ><<<512, 256, 0, stream>>>(x,  cw0, tau0, h1,  tf0);
    or_layer_k<1024,  512, 8, false><<<256, 256, 0, stream>>>(h1, cw1, tau1, h2,  tf1);
    or_layer_k< 512,  256, 4, false><<<256, 256, 0, stream>>>(h2, cw2, tau2, h3,  tf2);
    or_layer_k< 256,  128, 2, false><<<256, 256, 0, stream>>>(h3, cw3, tau3, out, tf3);
  }
}

// Round 9
// 135.832 us; speedup vs baseline: 2.4427x; 2.4427x over previous
//
#include <hip/hip_runtime.h>
#include <math.h>

// HW exp2 (v_exp_f32, quarter-rate trans pipe) when available.
#if defined(__has_builtin)
#  if __has_builtin(__builtin_amdgcn_exp2f)
#    define EXP2F(x) __builtin_amdgcn_exp2f(x)
#  endif
#endif
#ifndef EXP2F
#  define EXP2F(x) __expf(0.69314718055994530942f * (x))
#endif

// Full-rate exp2 (deg-3, rel err <= 6e-4, validated R4: absmax 0 at bf16).
// ~9 full-rate instrs; used on 1/4 of elements to rebalance trans vs VALU:
// per 64 z, trans 16 cy -> 12 cy, full-rate 6 cy -> 10.5 cy.
__device__ __forceinline__ float fast_exp2(float x) {
  const float M = 12582912.0f;             // 1.5 * 2^23
  const float y = x + M;                   // RNE(x) in mantissa
  const float n = y - M;
  const float f = x - n;                   // [-0.5, 0.5]
  float p = fmaf(f, 0.055504109f, 0.24022651f);
  p = fmaf(f, p, 0.69314718f);
  p = fmaf(f, p, 1.0f);                    // 2^f
  return __int_as_float((__float_as_int(y) << 23) + __float_as_int(p));
}

// ---------------------------------------------------------------------------
// 4-layer OR-gate net:
//   aw = leaky_clamp(W,0,1,0.1); z = h*aw
//   out[b,o] = sum_i z*softmax_i(tau*z); h' = 1-out
// Folding: arg = c2*z (c2 = tau*log2 e); e = exp2(arg); out = t/(s*c2).
//
// Structure (R8 lessons): NO cooperative fusion (grid.sync costs ~38 us each
// on this chip). Plain launches: prep (cw = c2*leaky_clamp(W), removes the
// clamp from the hot loop) + 4 layer kernels with a 3/4-HW 1/4-fast hybrid
// exp to balance the trans and full-rate pipes.
// ---------------------------------------------------------------------------

__device__ __forceinline__ float calc_c2(const float* tau_ptr, float tf) {
  const float ta  = tau_ptr[0];
  const float tau = tf + (ta >= 0.0f ? ta : 0.05f * ta);
  return tau * 1.44269504088896340736f;  // tau * log2(e)
}

__device__ __forceinline__ void prep_cw(const float* __restrict__ W,
                                        float* __restrict__ cw,
                                        int n4, float c2, int gtid, int gsz) {
  const float4* __restrict__ Wv = (const float4*)W;
  float4* __restrict__ Cv = (float4*)cw;
  for (int k = gtid; k < n4; k += gsz) {
    float4 v = Wv[k];
    float w[4] = {v.x, v.y, v.z, v.w};
    float o[4];
#pragma unroll
    for (int j = 0; j < 4; ++j) {
      const float m  = fminf(fmaxf(w[j], 0.0f), 1.0f);
      const float aw = fmaf(0.1f, w[j] - m, m);
      o[j] = c2 * aw;
    }
    float4 r; r.x = o[0]; r.y = o[1]; r.z = o[2]; r.w = o[3];
    Cv[k] = r;
  }
}

__launch_bounds__(256)
__global__ void prep_all(const float* __restrict__ W0, const float* __restrict__ W1,
                         const float* __restrict__ W2, const float* __restrict__ W3,
                         const float* __restrict__ tau0, const float* __restrict__ tau1,
                         const float* __restrict__ tau2, const float* __restrict__ tau3,
                         float* __restrict__ cw0, float* __restrict__ cw1,
                         float* __restrict__ cw2, float* __restrict__ cw3,
                         float tf0, float tf1, float tf2, float tf3) {
  const int gtid = blockIdx.x * 256 + threadIdx.x;
  const int gsz  = gridDim.x * 256;
  prep_cw(W0, cw0, 1024 * 1024 / 4, calc_c2(tau0, tf0), gtid, gsz);
  prep_cw(W1, cw1,  512 * 1024 / 4, calc_c2(tau1, tf1), gtid, gsz);
  prep_cw(W2, cw2,  256 *  512 / 4, calc_c2(tau2, tf2), gtid, gsz);
  prep_cw(W3, cw3,  128 *  256 / 4, calc_c2(tau3, tf3), gtid, gsz);
}

// One layer. lane = il(16 over i) x og(4 o-groups), OBB=2 outputs per group
// -> 8 outputs/wave; 4 waves/block -> 32 outputs/block; BB batch rows.
// grid = (OUT/32) * (128/BB).
template <int IN, int OUT, int BB, bool FIRST>
__launch_bounds__(256)
__global__ void or_layer_k(const float* __restrict__ hin,
                           const float* __restrict__ cw,
                           const float* __restrict__ tau_ptr,
                           float* __restrict__ hout, float tf) {
  constexpr int OBB = 2;
  constexpr int NIT = IN / 64;           // 16 lanes x float4 per iter
  constexpr int nOT = OUT / 32;

  const int tid  = threadIdx.x;
  const int bid  = blockIdx.x;
  const int lane = tid & 63;
  const int wid  = tid >> 6;
  const int il   = lane & 15;
  const int og   = lane >> 4;

  const int ot = bid % nOT;
  const int bt = bid / nOT;
  const int b0 = bt * BB;
  const int o0 = ot * 32 + wid * 8 + og * OBB;

  const float c2 = calc_c2(tau_ptr, tf);

  const float4* __restrict__ Cv = (const float4*)cw;
  const float4* __restrict__ Hv = (const float4*)hin;

  float s[BB][OBB], t[BB][OBB];
#pragma unroll
  for (int r = 0; r < BB; ++r)
#pragma unroll
    for (int c = 0; c < OBB; ++c) { s[r][c] = 0.0f; t[r][c] = 0.0f; }

#pragma unroll 2
  for (int ic = 0; ic < NIT; ++ic) {
    const int i4 = ic * 16 + il;

    float hc[BB][4];
    if (FIRST) {
      // hin is x: (128, IN/2); h = concat(x, 1-x); 64-float chunks align with
      // the IN/2 boundary -> uniform branch.
      constexpr int HALF4 = IN / 8;
      if (i4 < HALF4) {
#pragma unroll
        for (int r = 0; r < BB; ++r) {
          float4 v = Hv[(b0 + r) * HALF4 + i4];
          hc[r][0] = v.x; hc[r][1] = v.y; hc[r][2] = v.z; hc[r][3] = v.w;
        }
      } else {
#pragma unroll
        for (int r = 0; r < BB; ++r) {
          float4 v = Hv[(b0 + r) * HALF4 + (i4 - HALF4)];
          hc[r][0] = 1.0f - v.x; hc[r][1] = 1.0f - v.y;
          hc[r][2] = 1.0f - v.z; hc[r][3] = 1.0f - v.w;
        }
      }
    } else {
#pragma unroll
      for (int r = 0; r < BB; ++r) {
        float4 v = Hv[(b0 + r) * (IN / 4) + i4];
        hc[r][0] = v.x; hc[r][1] = v.y; hc[r][2] = v.z; hc[r][3] = v.w;
      }
    }

    float a[OBB][4];
#pragma unroll
    for (int c = 0; c < OBB; ++c) {
      float4 v = Cv[(o0 + c) * (IN / 4) + i4];
      a[c][0] = v.x; a[c][1] = v.y; a[c][2] = v.z; a[c][3] = v.w;
    }

#pragma unroll
    for (int r = 0; r < BB; ++r)
#pragma unroll
      for (int c = 0; c < OBB; ++c)
#pragma unroll
        for (int j = 0; j < 4; ++j) {
          const float arg = a[c][j] * hc[r][j];
          // Hybrid: j==3 on the full-rate pipe (f=1/4), rest on v_exp_f32.
          const float e = (j == 3) ? fast_exp2(arg) : EXP2F(arg);
          s[r][c] += e;
          t[r][c]  = fmaf(arg, e, t[r][c]);
        }
  }

  // Reduce across the 16 i-lanes of each group.
#pragma unroll
  for (int m = 1; m < 16; m <<= 1) {
#pragma unroll
    for (int r = 0; r < BB; ++r)
#pragma unroll
      for (int c = 0; c < OBB; ++c) {
        s[r][c] += __shfl_xor(s[r][c], m, 64);
        t[r][c] += __shfl_xor(t[r][c], m, 64);
      }
  }

  if (il == 0) {
    const float inv_c2 = 1.0f / c2;
#pragma unroll
    for (int r = 0; r < BB; ++r)
#pragma unroll
      for (int c = 0; c < OBB; ++c) {
        const float out = t[r][c] / s[r][c] * inv_c2;
        hout[(b0 + r) * OUT + (o0 + c)] = 1.0f - out;
      }
  }
}

extern "C" void kernel_launch(void* const* d_in, const int* in_sizes, int n_in,
                              void* d_out, int out_size, void* d_ws, size_t ws_size,
                              hipStream_t stream) {
  // setup_inputs() dict order: x, W0, tau0, W1, tau1, W2, tau2, W3, tau3
  const float* x    = (const float*)d_in[0];
  const float* W0   = (const float*)d_in[1];
  const float* tau0 = (const float*)d_in[2];
  const float* W1   = (const float*)d_in[3];
  const float* tau1 = (const float*)d_in[4];
  const float* W2   = (const float*)d_in[5];
  const float* tau2 = (const float*)d_in[6];
  const float* W3   = (const float*)d_in[7];
  const float* tau3 = (const float*)d_in[8];

  float* h1  = (float*)d_ws;             // 128*1024
  float* h2  = h1 + 128 * 1024;          // 128*512
  float* h3  = h2 + 128 * 512;           // 128*256
  float* cw0 = h3 + 128 * 256;           // 1024*1024
  float* cw1 = cw0 + 1024 * 1024;        // 512*1024
  float* cw2 = cw1 + 512 * 1024;         // 256*512
  float* cw3 = cw2 + 256 * 512;          // 128*256
  float* out = (float*)d_out;            // 128*128

  const double LOGR = 2.9444389791664403;  // log(0.95) - log(0.05) = log(19)
  float tf0 = (float)(log(1023.0) + LOGR);
  float tf1 = (float)(log(1023.0) + LOGR);
  float tf2 = (float)(log(511.0)  + LOGR);
  float tf3 = (float)(log(255.0)  + LOGR);

  prep_all<<<256, 256, 0, stream>>>(W0, W1, W2, W3, tau0, tau1, tau2, tau3,
                                    cw0, cw1, cw2, cw3, tf0, tf1, tf2, tf3);
  or_layer_k<1024, 1024, 8, true ><<<512, 256, 0, stream>>>(x,  cw0, tau0, h1,  tf0);
  or_layer_k<1024,  512, 8, false><<<256, 256, 0, stream>>>(h1, cw1, tau1, h2,  tf1);
  or_layer_k< 512,  256, 4, false><<<256, 256, 0, stream>>>(h2, cw2, tau2, h3,  tf2);
  or_layer_k< 256,  128, 2, false><<<256, 256, 0, stream>>>(h3, cw3, tau3, out, tf3);
}